// Round 4
// baseline (528.985 us; speedup 1.0000x reference)
//
#include <hip/hip_runtime.h>
#include <math.h>

#define N_NODES 50000
#define N_EDGES 800000
#define D 128
#define WGN 128          // ownership workgroups
#define NPW 391          // nodes per workgroup (128*391 = 50048 >= 50000)
#define NGROUP (N_EDGES / 8)   // 100000 u16x8 groups

typedef short bf16x8 __attribute__((ext_vector_type(8)));
typedef float f32x4 __attribute__((ext_vector_type(4)));
typedef unsigned short u16x8 __attribute__((ext_vector_type(8)));

static __device__ __forceinline__ unsigned short f2bf_rn(float f) {
    unsigned u = __float_as_uint(f);
    unsigned r = (u + 0x7FFF + ((u >> 16) & 1)) >> 16;
    return (unsigned short)r;
}
static __device__ __forceinline__ float bf2f(unsigned short h) {
    return __uint_as_float(((unsigned)h) << 16);
}

// ---------------- dst compression ----------------

__global__ __launch_bounds__(256) void compress_dst(const int* __restrict__ ei,
                                                    unsigned short* __restrict__ d16) {
    int e = blockIdx.x * 256 + threadIdx.x;
    if (e < N_EDGES) d16[e] = (unsigned short)ei[N_EDGES + e];
}

// ---------------- ownership count ----------------
// WG w owns dst nodes [w*NPW, min((w+1)*NPW, N)); streams all dst, LDS-counts its own.

__global__ __launch_bounds__(512) void count_own(const unsigned short* __restrict__ d16,
                                                 int* __restrict__ cnt) {
    __shared__ int lc[NPW];
    int t = threadIdx.x;
    int lo = blockIdx.x * NPW;
    int hi = lo + NPW; if (hi > N_NODES) hi = N_NODES;
    int nw = hi - lo;
    for (int j = t; j < nw; j += 512) lc[j] = 0;
    __syncthreads();
    const u16x8* dv = (const u16x8*)d16;
    for (int g = t; g < NGROUP; g += 512) {
        u16x8 v = dv[g];
        #pragma unroll
        for (int u = 0; u < 8; ++u) {
            int d = v[u];
            if (d >= lo && d < hi) atomicAdd(&lc[d - lo], 1);
        }
    }
    __syncthreads();
    for (int j = t; j < nw; j += 512) cnt[lo + j] = lc[j];
}

// ---------------- scan (cnt -> row_start), dinv ----------------

__global__ __launch_bounds__(256) void scan_reduce(const int* __restrict__ cnt, int* __restrict__ bsums) {
    int base = blockIdx.x * 512;
    int t = threadIdx.x;
    int i0 = base + 2 * t, i1 = i0 + 1;
    int s = 0;
    if (i0 < N_NODES) s += cnt[i0];
    if (i1 < N_NODES) s += cnt[i1];
    __shared__ int sm[256];
    sm[t] = s; __syncthreads();
    for (int o = 128; o > 0; o >>= 1) {
        if (t < o) sm[t] += sm[t + o];
        __syncthreads();
    }
    if (t == 0) bsums[blockIdx.x] = sm[0];
}

__global__ __launch_bounds__(128) void scan_blocksums(const int* __restrict__ bsums,
                                                      int* __restrict__ boffs,
                                                      int* __restrict__ row_start, int nb) {
    __shared__ int sm[128];
    int t = threadIdx.x;
    int v = (t < nb) ? bsums[t] : 0;
    sm[t] = v; __syncthreads();
    for (int o = 1; o < 128; o <<= 1) {
        int add = (t >= o) ? sm[t - o] : 0;
        __syncthreads();
        sm[t] += add;
        __syncthreads();
    }
    if (t < nb) boffs[t] = sm[t] - v;
    if (t == nb - 1) row_start[N_NODES] = sm[t];
}

__global__ __launch_bounds__(256) void scan_final(const int* __restrict__ cnt,
                                                  const int* __restrict__ boffs,
                                                  int* __restrict__ row_start,
                                                  float* __restrict__ dinv) {
    int base = blockIdx.x * 512;
    int t = threadIdx.x;
    int i0 = base + 2 * t, i1 = i0 + 1;
    int a = (i0 < N_NODES) ? cnt[i0] : 0;
    int b = (i1 < N_NODES) ? cnt[i1] : 0;
    int psum = a + b;
    __shared__ int sm[256];
    sm[t] = psum; __syncthreads();
    for (int o = 1; o < 256; o <<= 1) {
        int add = (t >= o) ? sm[t - o] : 0;
        __syncthreads();
        sm[t] += add;
        __syncthreads();
    }
    int excl = sm[t] - psum + boffs[blockIdx.x];
    if (i0 < N_NODES) {
        row_start[i0] = excl;
        dinv[i0] = rsqrtf((float)(a + 1));
    }
    if (i1 < N_NODES) {
        row_start[i1] = excl + a;
        dinv[i1] = rsqrtf((float)(b + 1));
    }
}

// ---------------- ownership scatter ----------------
// WG w streams all dst; for its own nodes, bumps an LDS cursor and writes the
// packed (dinv[src] , src) 8B record into its EXCLUSIVE contiguous CSR region.

__global__ __launch_bounds__(512) void scatter_own(const int* __restrict__ ei,
                                                   const unsigned short* __restrict__ d16,
                                                   const int* __restrict__ row_start,
                                                   const float* __restrict__ dinv,
                                                   unsigned long long* __restrict__ sed) {
    __shared__ int cur[NPW];
    int t = threadIdx.x;
    int lo = blockIdx.x * NPW;
    int hi = lo + NPW; if (hi > N_NODES) hi = N_NODES;
    int nw = hi - lo;
    for (int j = t; j < nw; j += 512) cur[j] = row_start[lo + j];
    __syncthreads();
    const u16x8* dv = (const u16x8*)d16;
    for (int g = t; g < NGROUP; g += 512) {
        u16x8 v = dv[g];
        #pragma unroll
        for (int u = 0; u < 8; ++u) {
            int d = v[u];
            if (d >= lo && d < hi) {
                int e = g * 8 + u;
                int src = ei[e];
                float dw = dinv[src];
                int p = atomicAdd(&cur[d - lo], 1);
                unsigned long long pk = ((unsigned long long)__float_as_uint(dw) << 32) | (unsigned)src;
                sed[p] = pk;
            }
        }
    }
}

// ---------------- W fragment prep (bf16 hi/lo, MFMA B-layout) ----------------

__global__ __launch_bounds__(256) void prep_w(const float* __restrict__ W,
                                              unsigned short* __restrict__ wH,
                                              unsigned short* __restrict__ wL) {
    int tid = blockIdx.x * 256 + threadIdx.x;   // 0..2047
    if (tid >= 2048) return;
    int kstep = tid >> 9;
    int ct = (tid >> 6) & 7;
    int lane = tid & 63;
    int kbase = kstep * 32 + ((lane >> 4) << 3);
    int c = ct * 16 + (lane & 15);
    #pragma unroll
    for (int e = 0; e < 8; ++e) {
        float v = W[(kbase + e) * 128 + c];
        unsigned short hb = f2bf_rn(v);
        float res = v - bf2f(hb);
        unsigned short lb = f2bf_rn(res);
        wH[tid * 8 + e] = hb;
        wL[tid * 8 + e] = lb;
    }
}

// ---------------- dense transform h = x @ W via bf16x3 MFMA ----------------

__global__ __launch_bounds__(256) void gemm_xw_mfma(const float* __restrict__ x,
                                                    const unsigned short* __restrict__ wH,
                                                    const unsigned short* __restrict__ wL,
                                                    float* __restrict__ h) {
    int wave = threadIdx.x >> 6;
    int lane = threadIdx.x & 63;
    int rowbase = blockIdx.x * 64 + wave * 16;

    f32x4 acc[8];
    #pragma unroll
    for (int ct = 0; ct < 8; ++ct) acc[ct] = (f32x4)(0.f);

    int arow = rowbase + (lane & 15);
    if (arow >= N_NODES) arow = N_NODES - 1;
    const float* xrow = x + arow * 128 + ((lane >> 4) << 3);

    #pragma unroll
    for (int kstep = 0; kstep < 4; ++kstep) {
        float4 a0 = *(const float4*)(xrow + kstep * 32);
        float4 a1 = *(const float4*)(xrow + kstep * 32 + 4);
        float av[8] = {a0.x, a0.y, a0.z, a0.w, a1.x, a1.y, a1.z, a1.w};
        bf16x8 ah, al;
        #pragma unroll
        for (int e = 0; e < 8; ++e) {
            unsigned short hb = f2bf_rn(av[e]);
            float res = av[e] - bf2f(hb);
            ah[e] = (short)hb;
            al[e] = (short)f2bf_rn(res);
        }
        const bf16x8* bh = (const bf16x8*)(wH + (size_t)(kstep * 8) * 64 * 8 + lane * 8);
        const bf16x8* bl = (const bf16x8*)(wL + (size_t)(kstep * 8) * 64 * 8 + lane * 8);
        #pragma unroll
        for (int ct = 0; ct < 8; ++ct) {
            bf16x8 bhv = bh[ct * 64];
            bf16x8 blv = bl[ct * 64];
            acc[ct] = __builtin_amdgcn_mfma_f32_16x16x32_bf16(ah, bhv, acc[ct], 0, 0, 0);
            acc[ct] = __builtin_amdgcn_mfma_f32_16x16x32_bf16(ah, blv, acc[ct], 0, 0, 0);
            acc[ct] = __builtin_amdgcn_mfma_f32_16x16x32_bf16(al, bhv, acc[ct], 0, 0, 0);
        }
    }

    int rbase = rowbase + ((lane >> 4) << 2);
    int col = lane & 15;
    #pragma unroll
    for (int ct = 0; ct < 8; ++ct) {
        #pragma unroll
        for (int i = 0; i < 4; ++i) {
            int row = rbase + i;
            if (row < N_NODES) h[row * 128 + ct * 16 + col] = acc[ct][i];
        }
    }
}

// ---------------- gather-aggregate (wave per node, packed CSR) ----------------
// out[i] = dinv[i] * sum_e dinv[src]*h[src] + dinv[i]^2*h[i] + b

__global__ __launch_bounds__(256) void aggregate(const float* __restrict__ h,
                                                 const int* __restrict__ row_start,
                                                 const unsigned long long* __restrict__ sed,
                                                 const float* __restrict__ dinv,
                                                 const float* __restrict__ bias,
                                                 float* __restrict__ out) {
    int node = blockIdx.x * 4 + (threadIdx.x >> 6);
    int lane = threadIdx.x & 63;
    if (node >= N_NODES) return;
    int s = row_start[node];
    int t = row_start[node + 1];
    float acc0 = 0.f, acc1 = 0.f;
    for (int base = s; base < t; base += 64) {
        int c = t - base;
        if (c > 64) c = 64;
        int li = base + (lane < c ? lane : c - 1);
        unsigned long long pk = sed[li];
        int idx = (int)(unsigned)(pk & 0xffffffffull);
        float dv = __uint_as_float((unsigned)(pk >> 32));
        int j = 0;
        for (; j + 4 <= c; j += 4) {
            int s0 = __shfl(idx, j), s1 = __shfl(idx, j + 1);
            int s2 = __shfl(idx, j + 2), s3 = __shfl(idx, j + 3);
            float d0 = __shfl(dv, j), d1 = __shfl(dv, j + 1);
            float d2 = __shfl(dv, j + 2), d3 = __shfl(dv, j + 3);
            const float* p0 = h + (size_t)s0 * 128 + lane;
            const float* p1 = h + (size_t)s1 * 128 + lane;
            const float* p2 = h + (size_t)s2 * 128 + lane;
            const float* p3 = h + (size_t)s3 * 128 + lane;
            float v00 = p0[0], v01 = p0[64];
            float v10 = p1[0], v11 = p1[64];
            float v20 = p2[0], v21 = p2[64];
            float v30 = p3[0], v31 = p3[64];
            acc0 += d0 * v00 + d1 * v10 + d2 * v20 + d3 * v30;
            acc1 += d0 * v01 + d1 * v11 + d2 * v21 + d3 * v31;
        }
        for (; j < c; ++j) {
            int sj = __shfl(idx, j);
            float dj = __shfl(dv, j);
            acc0 += dj * h[(size_t)sj * 128 + lane];
            acc1 += dj * h[(size_t)sj * 128 + 64 + lane];
        }
    }
    float di = dinv[node];
    out[(size_t)node * 128 + lane] = di * acc0 + di * di * h[(size_t)node * 128 + lane] + bias[lane];
    out[(size_t)node * 128 + 64 + lane] = di * acc1 + di * di * h[(size_t)node * 128 + 64 + lane] + bias[64 + lane];
}

// ---------------- launch ----------------

extern "C" void kernel_launch(void* const* d_in, const int* in_sizes, int n_in,
                              void* d_out, int out_size, void* d_ws, size_t ws_size,
                              hipStream_t stream) {
    const float* x  = (const float*)d_in[0];
    const int*   ei = (const int*)d_in[1];
    const float* W  = (const float*)d_in[2];
    const float* b  = (const float*)d_in[3];
    float* out = (float*)d_out;

    char* ws = (char*)d_ws;
    float* h              = (float*)(ws + 0);            // 25,600,000
    // d16 aliases the start of h: dead before gemm_xw_mfma writes h (stream-ordered)
    unsigned short* d16   = (unsigned short*)(ws + 0);   //  1,600,000 (alias)
    int*   cnt            = (int*)  (ws + 25600000);     //    200,000
    int*   row_start      = (int*)  (ws + 25800000);     //    200,004
    float* dinv           = (float*)(ws + 26000208);     //    200,000
    unsigned long long* sed = (unsigned long long*)(ws + 26200208); // 6,400,000
    int*   bsums          = (int*)  (ws + 32600208);     //        392
    int*   boffs          = (int*)  (ws + 32600608);     //        392
    unsigned short* wH    = (unsigned short*)(ws + 32601024); // 32,768
    unsigned short* wL    = (unsigned short*)(ws + 32633792); // 32,768

    const int nb = (N_NODES + 511) / 512;   // 98

    hipLaunchKernelGGL(compress_dst,   dim3((N_EDGES + 255) / 256), dim3(256), 0, stream, ei, d16);
    hipLaunchKernelGGL(count_own,      dim3(WGN), dim3(512), 0, stream, d16, cnt);
    hipLaunchKernelGGL(scan_reduce,    dim3(nb),  dim3(256), 0, stream, cnt, bsums);
    hipLaunchKernelGGL(scan_blocksums, dim3(1),   dim3(128), 0, stream, bsums, boffs, row_start, nb);
    hipLaunchKernelGGL(scan_final,     dim3(nb),  dim3(256), 0, stream, cnt, boffs, row_start, dinv);
    hipLaunchKernelGGL(scatter_own,    dim3(WGN), dim3(512), 0, stream, ei, d16, row_start, dinv, sed);
    hipLaunchKernelGGL(prep_w,         dim3(8),   dim3(256), 0, stream, W, wH, wL);
    hipLaunchKernelGGL(gemm_xw_mfma,   dim3((N_NODES + 63) / 64), dim3(256), 0, stream, x, wH, wL, h);
    hipLaunchKernelGGL(aggregate,      dim3((N_NODES + 3) / 4), dim3(256), 0, stream, h, row_start, sed, dinv, b, out);
}

// Round 5
// 215.679 us; speedup vs baseline: 2.4527x; 2.4527x over previous
//
#include <hip/hip_runtime.h>
#include <math.h>

#define N_NODES 50000
#define N_EDGES 800000
#define D 128

typedef short bf16x8 __attribute__((ext_vector_type(8)));
typedef float f32x4 __attribute__((ext_vector_type(4)));

static __device__ __forceinline__ unsigned short f2bf_rn(float f) {
    unsigned u = __float_as_uint(f);
    unsigned r = (u + 0x7FFF + ((u >> 16) & 1)) >> 16;
    return (unsigned short)r;
}
static __device__ __forceinline__ float bf2f(unsigned short h) {
    return __uint_as_float(((unsigned)h) << 16);
}

// ---------------- CSR build (counting sort, u16 entries) ----------------

__global__ __launch_bounds__(256) void zero_cnt(int* __restrict__ cnt) {
    int i = blockIdx.x * 256 + threadIdx.x;
    if (i < N_NODES) cnt[i] = 0;
}

__global__ __launch_bounds__(256) void count_deg(const int* __restrict__ ei, int* __restrict__ cnt) {
    int e = blockIdx.x * 256 + threadIdx.x;
    if (e >= N_EDGES) return;
    int dst = ei[N_EDGES + e];
    atomicAdd(&cnt[dst], 1);
}

__global__ __launch_bounds__(256) void scan_reduce(const int* __restrict__ cnt, int* __restrict__ bsums) {
    int base = blockIdx.x * 512;
    int t = threadIdx.x;
    int i0 = base + 2 * t, i1 = i0 + 1;
    int s = 0;
    if (i0 < N_NODES) s += cnt[i0];
    if (i1 < N_NODES) s += cnt[i1];
    __shared__ int sm[256];
    sm[t] = s; __syncthreads();
    for (int o = 128; o > 0; o >>= 1) {
        if (t < o) sm[t] += sm[t + o];
        __syncthreads();
    }
    if (t == 0) bsums[blockIdx.x] = sm[0];
}

__global__ __launch_bounds__(128) void scan_blocksums(const int* __restrict__ bsums,
                                                      int* __restrict__ boffs,
                                                      int* __restrict__ row_start, int nb) {
    __shared__ int sm[128];
    int t = threadIdx.x;
    int v = (t < nb) ? bsums[t] : 0;
    sm[t] = v; __syncthreads();
    for (int o = 1; o < 128; o <<= 1) {
        int add = (t >= o) ? sm[t - o] : 0;
        __syncthreads();
        sm[t] += add;
        __syncthreads();
    }
    if (t < nb) boffs[t] = sm[t] - v;
    if (t == nb - 1) row_start[N_NODES] = sm[t];
}

__global__ __launch_bounds__(256) void scan_final(const int* __restrict__ cnt,
                                                  const int* __restrict__ boffs,
                                                  int* __restrict__ row_start,
                                                  int* __restrict__ cursor,
                                                  float* __restrict__ dinv) {
    int base = blockIdx.x * 512;
    int t = threadIdx.x;
    int i0 = base + 2 * t, i1 = i0 + 1;
    int a = (i0 < N_NODES) ? cnt[i0] : 0;
    int b = (i1 < N_NODES) ? cnt[i1] : 0;
    int psum = a + b;
    __shared__ int sm[256];
    sm[t] = psum; __syncthreads();
    for (int o = 1; o < 256; o <<= 1) {
        int add = (t >= o) ? sm[t - o] : 0;
        __syncthreads();
        sm[t] += add;
        __syncthreads();
    }
    int excl = sm[t] - psum + boffs[blockIdx.x];
    if (i0 < N_NODES) {
        row_start[i0] = excl;
        cursor[i0] = excl;
        dinv[i0] = rsqrtf((float)(a + 1));
    }
    if (i1 < N_NODES) {
        row_start[i1] = excl + a;
        cursor[i1] = excl + a;
        dinv[i1] = rsqrtf((float)(b + 1));
    }
}

__global__ __launch_bounds__(256) void fill_csr(const int* __restrict__ ei,
                                                int* __restrict__ cursor,
                                                unsigned short* __restrict__ ssrc16) {
    int e = blockIdx.x * 256 + threadIdx.x;
    if (e >= N_EDGES) return;
    int src = ei[e];
    int dst = ei[N_EDGES + e];
    int p = atomicAdd(&cursor[dst], 1);
    ssrc16[p] = (unsigned short)src;
}

// ---------------- W fragment prep (bf16 hi/lo, MFMA B-layout) ----------------
// Lane l of fragment (kstep, ctile) holds B[k = kstep*32 + (l>>4)*8 + e][c = ctile*16 + (l&15)]

__global__ __launch_bounds__(256) void prep_w(const float* __restrict__ W,
                                              unsigned short* __restrict__ wH,
                                              unsigned short* __restrict__ wL) {
    int tid = blockIdx.x * 256 + threadIdx.x;   // 0..2047
    if (tid >= 2048) return;
    int kstep = tid >> 9;
    int ct = (tid >> 6) & 7;
    int lane = tid & 63;
    int kbase = kstep * 32 + ((lane >> 4) << 3);
    int c = ct * 16 + (lane & 15);
    #pragma unroll
    for (int e = 0; e < 8; ++e) {
        float v = W[(kbase + e) * 128 + c];
        unsigned short hb = f2bf_rn(v);
        float res = v - bf2f(hb);
        unsigned short lb = f2bf_rn(res);
        wH[tid * 8 + e] = hb;
        wL[tid * 8 + e] = lb;
    }
}

// ---------------- dense transform h = x @ W via bf16x3 MFMA, bf16 output ----------------

__global__ __launch_bounds__(256) void gemm_xw_mfma(const float* __restrict__ x,
                                                    const unsigned short* __restrict__ wH,
                                                    const unsigned short* __restrict__ wL,
                                                    unsigned short* __restrict__ h) {
    int wave = threadIdx.x >> 6;
    int lane = threadIdx.x & 63;
    int rowbase = blockIdx.x * 64 + wave * 16;

    f32x4 acc[8];
    #pragma unroll
    for (int ct = 0; ct < 8; ++ct) acc[ct] = (f32x4)(0.f);

    int arow = rowbase + (lane & 15);
    if (arow >= N_NODES) arow = N_NODES - 1;
    const float* xrow = x + (size_t)arow * 128 + ((lane >> 4) << 3);

    #pragma unroll
    for (int kstep = 0; kstep < 4; ++kstep) {
        float4 a0 = *(const float4*)(xrow + kstep * 32);
        float4 a1 = *(const float4*)(xrow + kstep * 32 + 4);
        float av[8] = {a0.x, a0.y, a0.z, a0.w, a1.x, a1.y, a1.z, a1.w};
        bf16x8 ah, al;
        #pragma unroll
        for (int e = 0; e < 8; ++e) {
            unsigned short hb = f2bf_rn(av[e]);
            float res = av[e] - bf2f(hb);
            ah[e] = (short)hb;
            al[e] = (short)f2bf_rn(res);
        }
        const bf16x8* bh = (const bf16x8*)(wH + (size_t)(kstep * 8) * 64 * 8 + lane * 8);
        const bf16x8* bl = (const bf16x8*)(wL + (size_t)(kstep * 8) * 64 * 8 + lane * 8);
        #pragma unroll
        for (int ct = 0; ct < 8; ++ct) {
            bf16x8 bhv = bh[ct * 64];
            bf16x8 blv = bl[ct * 64];
            acc[ct] = __builtin_amdgcn_mfma_f32_16x16x32_bf16(ah, bhv, acc[ct], 0, 0, 0);
            acc[ct] = __builtin_amdgcn_mfma_f32_16x16x32_bf16(ah, blv, acc[ct], 0, 0, 0);
            acc[ct] = __builtin_amdgcn_mfma_f32_16x16x32_bf16(al, bhv, acc[ct], 0, 0, 0);
        }
    }

    int rbase = rowbase + ((lane >> 4) << 2);
    int col = lane & 15;
    #pragma unroll
    for (int ct = 0; ct < 8; ++ct) {
        #pragma unroll
        for (int i = 0; i < 4; ++i) {
            int row = rbase + i;
            if (row < N_NODES) h[(size_t)row * 128 + ct * 16 + col] = f2bf_rn(acc[ct][i]);
        }
    }
}

// ---------------- gather-aggregate (wave per node, bf16 h, u16 CSR) ----------------
// out[i] = dinv[i] * sum_e dinv[src]*h[src] + dinv[i]^2*h[i] + b
// lane handles dims (2*lane, 2*lane+1) via one u32 (2x bf16) load per row.

__global__ __launch_bounds__(256) void aggregate(const unsigned int* __restrict__ hu,
                                                 const int* __restrict__ row_start,
                                                 const unsigned short* __restrict__ ssrc16,
                                                 const float* __restrict__ dinv,
                                                 const float* __restrict__ bias,
                                                 float* __restrict__ out) {
    int node = blockIdx.x * 4 + (threadIdx.x >> 6);
    int lane = threadIdx.x & 63;
    if (node >= N_NODES) return;
    int s = row_start[node];
    int t = row_start[node + 1];
    float accx = 0.f, accy = 0.f;
    for (int base = s; base < t; base += 64) {
        int c = t - base;
        if (c > 64) c = 64;
        int li = base + (lane < c ? lane : c - 1);
        int idx = (int)ssrc16[li];
        float dv = dinv[idx];
        int j = 0;
        for (; j + 4 <= c; j += 4) {
            int s0 = __shfl(idx, j), s1 = __shfl(idx, j + 1);
            int s2 = __shfl(idx, j + 2), s3 = __shfl(idx, j + 3);
            float d0 = __shfl(dv, j), d1 = __shfl(dv, j + 1);
            float d2 = __shfl(dv, j + 2), d3 = __shfl(dv, j + 3);
            unsigned u0 = hu[(size_t)s0 * 64 + lane];
            unsigned u1 = hu[(size_t)s1 * 64 + lane];
            unsigned u2 = hu[(size_t)s2 * 64 + lane];
            unsigned u3 = hu[(size_t)s3 * 64 + lane];
            accx += d0 * __uint_as_float(u0 << 16) + d1 * __uint_as_float(u1 << 16)
                  + d2 * __uint_as_float(u2 << 16) + d3 * __uint_as_float(u3 << 16);
            accy += d0 * __uint_as_float(u0 & 0xffff0000u) + d1 * __uint_as_float(u1 & 0xffff0000u)
                  + d2 * __uint_as_float(u2 & 0xffff0000u) + d3 * __uint_as_float(u3 & 0xffff0000u);
        }
        for (; j < c; ++j) {
            int sj = __shfl(idx, j);
            float dj = __shfl(dv, j);
            unsigned u = hu[(size_t)sj * 64 + lane];
            accx += dj * __uint_as_float(u << 16);
            accy += dj * __uint_as_float(u & 0xffff0000u);
        }
    }
    float di = dinv[node];
    unsigned us = hu[(size_t)node * 64 + lane];
    float2 bv = *(const float2*)&bias[2 * lane];
    float2 o;
    o.x = di * accx + di * di * __uint_as_float(us << 16) + bv.x;
    o.y = di * accy + di * di * __uint_as_float(us & 0xffff0000u) + bv.y;
    *(float2*)&out[(size_t)node * 128 + 2 * lane] = o;
}

// ---------------- launch ----------------

extern "C" void kernel_launch(void* const* d_in, const int* in_sizes, int n_in,
                              void* d_out, int out_size, void* d_ws, size_t ws_size,
                              hipStream_t stream) {
    const float* x  = (const float*)d_in[0];
    const int*   ei = (const int*)d_in[1];
    const float* W  = (const float*)d_in[2];
    const float* b  = (const float*)d_in[3];
    float* out = (float*)d_out;

    char* ws = (char*)d_ws;
    unsigned short* h     = (unsigned short*)(ws + 0);   // 12,800,000
    int*   cnt            = (int*)  (ws + 12800000);     //    200,000
    int*   row_start      = (int*)  (ws + 13000000);     //    200,004
    int*   cursor         = (int*)  (ws + 13200016);     //    200,000
    float* dinv           = (float*)(ws + 13400016);     //    200,000
    unsigned short* ssrc16 = (unsigned short*)(ws + 13600016); // 1,600,000
    int*   bsums          = (int*)  (ws + 15200016);     //        392
    int*   boffs          = (int*)  (ws + 15200416);     //        392
    unsigned short* wH    = (unsigned short*)(ws + 15200832); // 32,768
    unsigned short* wL    = (unsigned short*)(ws + 15233600); // 32,768

    const int nb = (N_NODES + 511) / 512;   // 98

    hipLaunchKernelGGL(zero_cnt,       dim3((N_NODES + 255) / 256), dim3(256), 0, stream, cnt);
    hipLaunchKernelGGL(count_deg,      dim3((N_EDGES + 255) / 256), dim3(256), 0, stream, ei, cnt);
    hipLaunchKernelGGL(scan_reduce,    dim3(nb),  dim3(256), 0, stream, cnt, bsums);
    hipLaunchKernelGGL(scan_blocksums, dim3(1),   dim3(128), 0, stream, bsums, boffs, row_start, nb);
    hipLaunchKernelGGL(scan_final,     dim3(nb),  dim3(256), 0, stream, cnt, boffs, row_start, cursor, dinv);
    hipLaunchKernelGGL(fill_csr,       dim3((N_EDGES + 255) / 256), dim3(256), 0, stream, ei, cursor, ssrc16);
    hipLaunchKernelGGL(prep_w,         dim3(8),   dim3(256), 0, stream, W, wH, wL);
    hipLaunchKernelGGL(gemm_xw_mfma,   dim3((N_NODES + 63) / 64), dim3(256), 0, stream, x, wH, wL, h);
    hipLaunchKernelGGL(aggregate,      dim3((N_NODES + 3) / 4), dim3(256), 0, stream,
                       (const unsigned int*)h, row_start, ssrc16, dinv, b, out);
}

// Round 7
// 163.043 us; speedup vs baseline: 3.2445x; 1.3228x over previous
//
#include <hip/hip_runtime.h>
#include <math.h>

#define N_NODES 50000
#define N_EDGES 800000
#define D 128
#define NBKT 392            // buckets of 128 dst nodes: 392*128 = 50176 >= 50000
#define CHUNK 4096          // edges per partition block
#define NCHUNK ((N_EDGES + CHUNK - 1) / CHUNK)   // 196
#define CAPB 4096           // partition capacity per bucket (avg 2041, max ~2300)

typedef short bf16x8 __attribute__((ext_vector_type(8)));
typedef float f32x4 __attribute__((ext_vector_type(4)));

static __device__ __forceinline__ unsigned short f2bf_rn(float f) {
    unsigned u = __float_as_uint(f);
    unsigned r = (u + 0x7FFF + ((u >> 16) & 1)) >> 16;
    return (unsigned short)r;
}
static __device__ __forceinline__ float bf2f(unsigned short h) {
    return __uint_as_float(((unsigned)h) << 16);
}

// ---------------- pass 1: compress edges to u16 + bucket histogram ----------------

__global__ __launch_bounds__(256) void compress_hist(const int* __restrict__ ei,
                                                     unsigned short* __restrict__ s16,
                                                     unsigned short* __restrict__ d16,
                                                     int* __restrict__ bcnt) {
    __shared__ int lh[NBKT];
    int t = threadIdx.x;
    for (int j = t; j < NBKT; j += 256) lh[j] = 0;
    __syncthreads();
    for (int e = blockIdx.x * 256 + t; e < N_EDGES; e += gridDim.x * 256) {
        int s = ei[e];
        int d = ei[N_EDGES + e];
        s16[e] = (unsigned short)s;
        d16[e] = (unsigned short)d;
        atomicAdd(&lh[d >> 7], 1);
    }
    __syncthreads();
    for (int j = t; j < NBKT; j += 256) {
        int c = lh[j];
        if (c) atomicAdd(&bcnt[j], c);
    }
}

// ---------------- pass 2: scan bucket counts -> bases; init cursors ----------------

__global__ __launch_bounds__(256) void bscan(const int* __restrict__ bcnt,
                                             int* __restrict__ bbase,
                                             int* __restrict__ gcur,
                                             int* __restrict__ row_start) {
    __shared__ int sm[256];
    int t = threadIdx.x;
    int i0 = 2 * t, i1 = i0 + 1;
    int a = (i0 < NBKT) ? bcnt[i0] : 0;
    int b = (i1 < NBKT) ? bcnt[i1] : 0;
    int ps = a + b;
    sm[t] = ps; __syncthreads();
    for (int o = 1; o < 256; o <<= 1) {
        int ad = (t >= o) ? sm[t - o] : 0;
        __syncthreads();
        sm[t] += ad;
        __syncthreads();
    }
    int ex = sm[t] - ps;
    if (i0 < NBKT) { bbase[i0] = ex;     gcur[i0] = i0 * CAPB; }
    if (i1 < NBKT) { bbase[i1] = ex + a; gcur[i1] = i1 * CAPB; }
    if (t == 0) row_start[N_NODES] = N_EDGES;
}

// ---------------- pass 3: LDS-ordered partition into bucket regions ----------------
// Each block: chunk of 4096 edges -> LDS hist -> LDS scan -> LDS placement ->
// one global atomic per nonempty bucket -> sequential coalesced flush.

__global__ __launch_bounds__(256) void partition(const unsigned short* __restrict__ s16,
                                                 const unsigned short* __restrict__ d16,
                                                 int* __restrict__ gcur,
                                                 unsigned int* __restrict__ part) {
    __shared__ unsigned int ebuf[CHUNK];   // 16 KB
    __shared__ unsigned int obuf[CHUNK];   // 16 KB
    __shared__ int hist[NBKT];
    __shared__ int spos[NBKT];
    __shared__ int goff[NBKT];
    __shared__ int sm[256];
    int t = threadIdx.x;
    int base = blockIdx.x * CHUNK;
    int n = N_EDGES - base; if (n > CHUNK) n = CHUNK;

    for (int j = t; j < NBKT; j += 256) hist[j] = 0;
    __syncthreads();
    for (int i = t; i < n; i += 256) {
        unsigned s = s16[base + i];
        unsigned d = d16[base + i];
        ebuf[i] = s | (d << 16);
        atomicAdd(&hist[d >> 7], 1);
    }
    __syncthreads();
    // exclusive scan of hist[NBKT] (pairwise, 256 threads over 512 padded)
    int i0 = 2 * t, i1 = i0 + 1;
    int a = (i0 < NBKT) ? hist[i0] : 0;
    int b = (i1 < NBKT) ? hist[i1] : 0;
    int ps = a + b;
    sm[t] = ps; __syncthreads();
    for (int o = 1; o < 256; o <<= 1) {
        int ad = (t >= o) ? sm[t - o] : 0;
        __syncthreads();
        sm[t] += ad;
        __syncthreads();
    }
    int ex = sm[t] - ps;
    if (i0 < NBKT) spos[i0] = ex;
    if (i1 < NBKT) spos[i1] = ex + a;
    __syncthreads();
    // reserve global slices (one atomic per bucket)
    for (int j = t; j < NBKT; j += 256) {
        int gp = atomicAdd(&gcur[j], hist[j]);
        goff[j] = gp - spos[j];
    }
    __syncthreads();
    for (int j = t; j < NBKT; j += 256) hist[j] = 0;
    __syncthreads();
    // LDS placement in bucket order
    for (int i = t; i < n; i += 256) {
        unsigned e = ebuf[i];
        int bk = e >> 23;
        int p = spos[bk] + atomicAdd(&hist[bk], 1);
        obuf[p] = e;
    }
    __syncthreads();
    // sequential flush: consecutive i within a bucket -> consecutive global addrs
    for (int i = t; i < n; i += 256) {
        unsigned e = obuf[i];
        int bk = e >> 23;
        part[goff[bk] + i] = e;
    }
}

// ---------------- pass 4: per-bucket CSR build (exclusive regions, LDS image) ----------------

__global__ __launch_bounds__(256) void csr_build(const unsigned int* __restrict__ part,
                                                 const int* __restrict__ bcnt,
                                                 const int* __restrict__ bbase,
                                                 int* __restrict__ row_start,
                                                 float* __restrict__ dinv,
                                                 unsigned short* __restrict__ ssrc16) {
    __shared__ unsigned int ebuf[CAPB];        // 16 KB
    __shared__ unsigned short img[CAPB];       // 8 KB
    __shared__ int h128[128];
    __shared__ int loff[128];
    __shared__ int sm[128];
    int t = threadIdx.x;
    int b = blockIdx.x;
    int cnt = bcnt[b];
    int gb = b * CAPB;
    int cb = bbase[b];
    int nbase = b * 128;

    for (int j = t; j < 128; j += 256) h128[j] = 0;
    __syncthreads();
    for (int i = t; i < cnt; i += 256) {
        unsigned e = part[gb + i];
        ebuf[i] = e;
        atomicAdd(&h128[(e >> 16) & 127], 1);
    }
    __syncthreads();
    if (t < 128) sm[t] = h128[t];
    __syncthreads();
    for (int o = 1; o < 128; o <<= 1) {
        int ad = 0;
        if (t < 128 && t >= o) ad = sm[t - o];
        __syncthreads();
        if (t < 128) sm[t] += ad;
        __syncthreads();
    }
    if (t < 128) {
        int ex = sm[t] - h128[t];
        loff[t] = ex;
        int node = nbase + t;
        if (node < N_NODES) {
            row_start[node] = cb + ex;
            dinv[node] = rsqrtf((float)(h128[t] + 1));
        }
        h128[t] = 0;   // reuse as placement cursor
    }
    __syncthreads();
    for (int i = t; i < cnt; i += 256) {
        unsigned e = ebuf[i];
        int j = (e >> 16) & 127;
        int p = loff[j] + atomicAdd(&h128[j], 1);
        img[p] = (unsigned short)(e & 0xffffu);
    }
    __syncthreads();
    for (int i = t; i < cnt; i += 256) ssrc16[cb + i] = img[i];
}

// ---------------- W fragment prep (bf16 hi/lo, MFMA B-layout) ----------------

__global__ __launch_bounds__(256) void prep_w(const float* __restrict__ W,
                                              unsigned short* __restrict__ wH,
                                              unsigned short* __restrict__ wL) {
    int tid = blockIdx.x * 256 + threadIdx.x;   // 0..2047
    if (tid >= 2048) return;
    int kstep = tid >> 9;
    int ct = (tid >> 6) & 7;
    int lane = tid & 63;
    int kbase = kstep * 32 + ((lane >> 4) << 3);
    int c = ct * 16 + (lane & 15);
    #pragma unroll
    for (int e = 0; e < 8; ++e) {
        float v = W[(kbase + e) * 128 + c];
        unsigned short hb = f2bf_rn(v);
        float res = v - bf2f(hb);
        unsigned short lb = f2bf_rn(res);
        wH[tid * 8 + e] = hb;
        wL[tid * 8 + e] = lb;
    }
}

// ---------------- dense transform h = x @ W via bf16x3 MFMA, bf16 output ----------------

__global__ __launch_bounds__(256) void gemm_xw_mfma(const float* __restrict__ x,
                                                    const unsigned short* __restrict__ wH,
                                                    const unsigned short* __restrict__ wL,
                                                    unsigned short* __restrict__ h) {
    int wave = threadIdx.x >> 6;
    int lane = threadIdx.x & 63;
    int rowbase = blockIdx.x * 64 + wave * 16;

    f32x4 acc[8];
    #pragma unroll
    for (int ct = 0; ct < 8; ++ct) acc[ct] = (f32x4)(0.f);

    int arow = rowbase + (lane & 15);
    if (arow >= N_NODES) arow = N_NODES - 1;
    const float* xrow = x + (size_t)arow * 128 + ((lane >> 4) << 3);

    #pragma unroll
    for (int kstep = 0; kstep < 4; ++kstep) {
        float4 a0 = *(const float4*)(xrow + kstep * 32);
        float4 a1 = *(const float4*)(xrow + kstep * 32 + 4);
        float av[8] = {a0.x, a0.y, a0.z, a0.w, a1.x, a1.y, a1.z, a1.w};
        bf16x8 ah, al;
        #pragma unroll
        for (int e = 0; e < 8; ++e) {
            unsigned short hb = f2bf_rn(av[e]);
            float res = av[e] - bf2f(hb);
            ah[e] = (short)hb;
            al[e] = (short)f2bf_rn(res);
        }
        const bf16x8* bh = (const bf16x8*)(wH + (size_t)(kstep * 8) * 64 * 8 + lane * 8);
        const bf16x8* bl = (const bf16x8*)(wL + (size_t)(kstep * 8) * 64 * 8 + lane * 8);
        #pragma unroll
        for (int ct = 0; ct < 8; ++ct) {
            bf16x8 bhv = bh[ct * 64];
            bf16x8 blv = bl[ct * 64];
            acc[ct] = __builtin_amdgcn_mfma_f32_16x16x32_bf16(ah, bhv, acc[ct], 0, 0, 0);
            acc[ct] = __builtin_amdgcn_mfma_f32_16x16x32_bf16(ah, blv, acc[ct], 0, 0, 0);
            acc[ct] = __builtin_amdgcn_mfma_f32_16x16x32_bf16(al, bhv, acc[ct], 0, 0, 0);
        }
    }

    int rbase = rowbase + ((lane >> 4) << 2);
    int col = lane & 15;
    #pragma unroll
    for (int ct = 0; ct < 8; ++ct) {
        #pragma unroll
        for (int i = 0; i < 4; ++i) {
            int row = rbase + i;
            if (row < N_NODES) h[(size_t)row * 128 + ct * 16 + col] = f2bf_rn(acc[ct][i]);
        }
    }
}

// ---------------- gather-aggregate (wave per node, bf16 h, u16 CSR) ----------------

__global__ __launch_bounds__(256) void aggregate(const unsigned int* __restrict__ hu,
                                                 const int* __restrict__ row_start,
                                                 const unsigned short* __restrict__ ssrc16,
                                                 const float* __restrict__ dinv,
                                                 const float* __restrict__ bias,
                                                 float* __restrict__ out) {
    int node = blockIdx.x * 4 + (threadIdx.x >> 6);
    int lane = threadIdx.x & 63;
    if (node >= N_NODES) return;
    int s = row_start[node];
    int t = row_start[node + 1];
    float accx = 0.f, accy = 0.f;
    for (int base = s; base < t; base += 64) {
        int c = t - base;
        if (c > 64) c = 64;
        int li = base + (lane < c ? lane : c - 1);
        int idx = (int)ssrc16[li];
        float dv = dinv[idx];
        int j = 0;
        for (; j + 4 <= c; j += 4) {
            int s0 = __shfl(idx, j), s1 = __shfl(idx, j + 1);
            int s2 = __shfl(idx, j + 2), s3 = __shfl(idx, j + 3);
            float d0 = __shfl(dv, j), d1 = __shfl(dv, j + 1);
            float d2 = __shfl(dv, j + 2), d3 = __shfl(dv, j + 3);
            unsigned u0 = hu[(size_t)s0 * 64 + lane];
            unsigned u1 = hu[(size_t)s1 * 64 + lane];
            unsigned u2 = hu[(size_t)s2 * 64 + lane];
            unsigned u3 = hu[(size_t)s3 * 64 + lane];
            accx += d0 * __uint_as_float(u0 << 16) + d1 * __uint_as_float(u1 << 16)
                  + d2 * __uint_as_float(u2 << 16) + d3 * __uint_as_float(u3 << 16);
            accy += d0 * __uint_as_float(u0 & 0xffff0000u) + d1 * __uint_as_float(u1 & 0xffff0000u)
                  + d2 * __uint_as_float(u2 & 0xffff0000u) + d3 * __uint_as_float(u3 & 0xffff0000u);
        }
        for (; j < c; ++j) {
            int sj = __shfl(idx, j);
            float dj = __shfl(dv, j);
            unsigned u = hu[(size_t)sj * 64 + lane];
            accx += dj * __uint_as_float(u << 16);
            accy += dj * __uint_as_float(u & 0xffff0000u);
        }
    }
    float di = dinv[node];
    unsigned us = hu[(size_t)node * 64 + lane];
    float2 bv = *(const float2*)&bias[2 * lane];
    float2 o;
    o.x = di * accx + di * di * __uint_as_float(us << 16) + bv.x;
    o.y = di * accy + di * di * __uint_as_float(us & 0xffff0000u) + bv.y;
    *(float2*)&out[(size_t)node * 128 + 2 * lane] = o;
}

// ---------------- launch ----------------

extern "C" void kernel_launch(void* const* d_in, const int* in_sizes, int n_in,
                              void* d_out, int out_size, void* d_ws, size_t ws_size,
                              hipStream_t stream) {
    const float* x  = (const float*)d_in[0];
    const int*   ei = (const int*)d_in[1];
    const float* W  = (const float*)d_in[2];
    const float* b  = (const float*)d_in[3];
    float* out = (float*)d_out;

    char* ws = (char*)d_ws;
    // h occupies [0, 12.8MB); s16/d16/part alias its prefix (all dead before gemm writes h)
    unsigned short* h      = (unsigned short*)(ws + 0);        // 12,800,000
    unsigned short* s16    = (unsigned short*)(ws + 0);        //  1,600,000 (alias)
    unsigned short* d16    = (unsigned short*)(ws + 1600000);  //  1,600,000 (alias)
    unsigned int*   part   = (unsigned int*)  (ws + 3200000);  //  6,422,528 (alias)
    int*   row_start       = (int*)  (ws + 12800000);          //    200,004
    float* dinv            = (float*)(ws + 13000016);          //    200,000
    unsigned short* ssrc16 = (unsigned short*)(ws + 13200016); //  1,600,000
    int*   bcnt            = (int*)  (ws + 14800016);          //      1,568
    int*   bbase           = (int*)  (ws + 14801600);          //      1,568
    int*   gcur            = (int*)  (ws + 14803200);          //      1,568
    unsigned short* wH     = (unsigned short*)(ws + 14804800); //     32,768
    unsigned short* wL     = (unsigned short*)(ws + 14837568); //     32,768

    hipMemsetAsync(bcnt, 0, NBKT * sizeof(int), stream);
    hipLaunchKernelGGL(compress_hist, dim3(256),    dim3(256), 0, stream, ei, s16, d16, bcnt);
    hipLaunchKernelGGL(bscan,         dim3(1),      dim3(256), 0, stream, bcnt, bbase, gcur, row_start);
    hipLaunchKernelGGL(partition,     dim3(NCHUNK), dim3(256), 0, stream, s16, d16, gcur, part);
    hipLaunchKernelGGL(csr_build,     dim3(NBKT),   dim3(256), 0, stream, part, bcnt, bbase, row_start, dinv, ssrc16);
    hipLaunchKernelGGL(prep_w,        dim3(8),      dim3(256), 0, stream, W, wH, wL);
    hipLaunchKernelGGL(gemm_xw_mfma,  dim3((N_NODES + 63) / 64), dim3(256), 0, stream, x, wH, wL, h);
    hipLaunchKernelGGL(aggregate,     dim3((N_NODES + 3) / 4), dim3(256), 0, stream,
                       (const unsigned int*)h, row_start, ssrc16, dinv, b, out);
}

// Round 9
// 149.516 us; speedup vs baseline: 3.5380x; 1.0905x over previous
//
#include <hip/hip_runtime.h>
#include <math.h>

#define N_NODES 50000
#define N_EDGES 800000
#define D 128
#define NBKT 392            // buckets of 128 dst nodes: 392*128 = 50176 >= 50000
#define CHUNK 4096          // edges per partition block
#define NCHUNK ((N_EDGES + CHUNK - 1) / CHUNK)   // 196
#define CAPB 4096           // partition slot capacity per bucket (avg 2041, max ~2300)

typedef short bf16x8 __attribute__((ext_vector_type(8)));
typedef float f32x4 __attribute__((ext_vector_type(4)));

static __device__ __forceinline__ unsigned short f2bf_rn(float f) {
    unsigned u = __float_as_uint(f);
    unsigned r = (u + 0x7FFF + ((u >> 16) & 1)) >> 16;
    return (unsigned short)r;
}
static __device__ __forceinline__ float bf2f(unsigned short h) {
    return __uint_as_float(((unsigned)h) << 16);
}

// ---------------- setup: W fragments (blocks 0-7) + gcur init (block 8) ----------------
// W fragment for mfma_f32_16x16x32_bf16 B operand: lane l of frag (kstep, ctile) holds
// B[k = kstep*32 + (l>>4)*8 + e][c = ctile*16 + (l&15)], e = 0..7.

__global__ __launch_bounds__(256) void setup(const float* __restrict__ W,
                                             unsigned short* __restrict__ wH,
                                             unsigned short* __restrict__ wL,
                                             int* __restrict__ gcur,
                                             int* __restrict__ row_start) {
    if (blockIdx.x < 8) {
        int tid = blockIdx.x * 256 + threadIdx.x;   // 0..2047
        int kstep = tid >> 9;
        int ct = (tid >> 6) & 7;
        int lane = tid & 63;
        int kbase = kstep * 32 + ((lane >> 4) << 3);
        int c = ct * 16 + (lane & 15);
        #pragma unroll
        for (int e = 0; e < 8; ++e) {
            float v = W[(kbase + e) * 128 + c];
            unsigned short hb = f2bf_rn(v);
            float res = v - bf2f(hb);
            wH[tid * 8 + e] = hb;
            wL[tid * 8 + e] = f2bf_rn(res);
        }
    } else {
        for (int j = threadIdx.x; j < NBKT; j += 256) gcur[j] = j * CAPB;
        if (threadIdx.x == 0) row_start[N_NODES] = N_EDGES;
    }
}

// ---------------- pass 1: LDS-ordered partition into fixed bucket regions ----------------
// Each block: chunk of 4096 edges (read from ei directly) -> LDS hist -> LDS scan ->
// LDS placement -> one global atomic per bucket -> sequential coalesced flush.

__global__ __launch_bounds__(256) void partition(const int* __restrict__ ei,
                                                 int* __restrict__ gcur,
                                                 unsigned int* __restrict__ part) {
    __shared__ unsigned int ebuf[CHUNK];   // 16 KB
    __shared__ unsigned int obuf[CHUNK];   // 16 KB
    __shared__ int hist[NBKT];
    __shared__ int spos[NBKT];
    __shared__ int goff[NBKT];
    __shared__ int sm[256];
    int t = threadIdx.x;
    int base = blockIdx.x * CHUNK;
    int n = N_EDGES - base; if (n > CHUNK) n = CHUNK;

    for (int j = t; j < NBKT; j += 256) hist[j] = 0;
    __syncthreads();
    for (int i = t; i < n; i += 256) {
        unsigned s = (unsigned)ei[base + i];
        unsigned d = (unsigned)ei[N_EDGES + base + i];
        ebuf[i] = s | (d << 16);
        atomicAdd(&hist[d >> 7], 1);
    }
    __syncthreads();
    // exclusive scan of hist[NBKT]
    int i0 = 2 * t, i1 = i0 + 1;
    int a = (i0 < NBKT) ? hist[i0] : 0;
    int b = (i1 < NBKT) ? hist[i1] : 0;
    int ps = a + b;
    sm[t] = ps; __syncthreads();
    for (int o = 1; o < 256; o <<= 1) {
        int ad = (t >= o) ? sm[t - o] : 0;
        __syncthreads();
        sm[t] += ad;
        __syncthreads();
    }
    int ex = sm[t] - ps;
    if (i0 < NBKT) spos[i0] = ex;
    if (i1 < NBKT) spos[i1] = ex + a;
    __syncthreads();
    // reserve global slices (one atomic per bucket)
    for (int j = t; j < NBKT; j += 256) {
        int gp = atomicAdd(&gcur[j], hist[j]);
        goff[j] = gp - spos[j];
    }
    __syncthreads();
    for (int j = t; j < NBKT; j += 256) hist[j] = 0;
    __syncthreads();
    // LDS placement in bucket order
    for (int i = t; i < n; i += 256) {
        unsigned e = ebuf[i];
        int bk = e >> 23;
        int p = spos[bk] + atomicAdd(&hist[bk], 1);
        obuf[p] = e;
    }
    __syncthreads();
    // sequential flush: consecutive i within a bucket -> consecutive global addrs
    for (int i = t; i < n; i += 256) {
        unsigned e = obuf[i];
        int bk = e >> 23;
        part[goff[bk] + i] = e;
    }
}

// ---------------- pass 2: per-bucket CSR build (self-computed prefix, LDS image) ----------------

__global__ __launch_bounds__(256) void csr_build(const unsigned int* __restrict__ part,
                                                 const int* __restrict__ gcur,
                                                 int* __restrict__ row_start,
                                                 float* __restrict__ dinv,
                                                 unsigned short* __restrict__ ssrc16) {
    __shared__ unsigned int ebuf[CAPB];        // 16 KB
    __shared__ unsigned short img[CAPB];       // 8 KB
    __shared__ int exf[NBKT];
    __shared__ int sm2[256];
    __shared__ int h128[128];
    __shared__ int loff[128];
    __shared__ int sm[128];
    int t = threadIdx.x;
    int b = blockIdx.x;

    // global prefix over bucket counts (cnt[j] = gcur[j] - j*CAPB)
    int i0 = 2 * t, i1 = i0 + 1;
    int a = (i0 < NBKT) ? (gcur[i0] - i0 * CAPB) : 0;
    int b2 = (i1 < NBKT) ? (gcur[i1] - i1 * CAPB) : 0;
    int ps = a + b2;
    sm2[t] = ps; __syncthreads();
    for (int o = 1; o < 256; o <<= 1) {
        int ad = (t >= o) ? sm2[t - o] : 0;
        __syncthreads();
        sm2[t] += ad;
        __syncthreads();
    }
    int ex = sm2[t] - ps;
    if (i0 < NBKT) exf[i0] = ex;
    if (i1 < NBKT) exf[i1] = ex + a;
    for (int j = t; j < 128; j += 256) h128[j] = 0;
    __syncthreads();

    int cnt = gcur[b] - b * CAPB;
    int cb = exf[b];
    int gb = b * CAPB;
    int nbase = b * 128;

    for (int i = t; i < cnt; i += 256) {
        unsigned e = part[gb + i];
        ebuf[i] = e;
        atomicAdd(&h128[(e >> 16) & 127], 1);
    }
    __syncthreads();
    if (t < 128) sm[t] = h128[t];
    __syncthreads();
    for (int o = 1; o < 128; o <<= 1) {
        int ad = 0;
        if (t < 128 && t >= o) ad = sm[t - o];
        __syncthreads();
        if (t < 128) sm[t] += ad;
        __syncthreads();
    }
    if (t < 128) {
        int exl = sm[t] - h128[t];
        loff[t] = exl;
        int node = nbase + t;
        if (node < N_NODES) {
            row_start[node] = cb + exl;
            dinv[node] = rsqrtf((float)(h128[t] + 1));
        }
        h128[t] = 0;   // reuse as placement cursor
    }
    __syncthreads();
    for (int i = t; i < cnt; i += 256) {
        unsigned e = ebuf[i];
        int j = (e >> 16) & 127;
        int p = loff[j] + atomicAdd(&h128[j], 1);
        img[p] = (unsigned short)(e & 0xffffu);
    }
    __syncthreads();
    for (int i = t; i < cnt; i += 256) ssrc16[cb + i] = img[i];
}

// ---------------- dense transform h = x @ W via bf16x3 MFMA, bf16 output ----------------

__global__ __launch_bounds__(256) void gemm_xw_mfma(const float* __restrict__ x,
                                                    const unsigned short* __restrict__ wH,
                                                    const unsigned short* __restrict__ wL,
                                                    unsigned short* __restrict__ h) {
    int wave = threadIdx.x >> 6;
    int lane = threadIdx.x & 63;
    int rowbase = blockIdx.x * 64 + wave * 16;

    f32x4 acc[8];
    #pragma unroll
    for (int ct = 0; ct < 8; ++ct) acc[ct] = (f32x4)(0.f);

    int arow = rowbase + (lane & 15);
    if (arow >= N_NODES) arow = N_NODES - 1;
    const float* xrow = x + (size_t)arow * 128 + ((lane >> 4) << 3);

    #pragma unroll
    for (int kstep = 0; kstep < 4; ++kstep) {
        float4 a0 = *(const float4*)(xrow + kstep * 32);
        float4 a1 = *(const float4*)(xrow + kstep * 32 + 4);
        float av[8] = {a0.x, a0.y, a0.z, a0.w, a1.x, a1.y, a1.z, a1.w};
        bf16x8 ah, al;
        #pragma unroll
        for (int e = 0; e < 8; ++e) {
            unsigned short hb = f2bf_rn(av[e]);
            float res = av[e] - bf2f(hb);
            ah[e] = (short)hb;
            al[e] = (short)f2bf_rn(res);
        }
        const bf16x8* bh = (const bf16x8*)(wH + (size_t)(kstep * 8) * 64 * 8 + lane * 8);
        const bf16x8* bl = (const bf16x8*)(wL + (size_t)(kstep * 8) * 64 * 8 + lane * 8);
        #pragma unroll
        for (int ct = 0; ct < 8; ++ct) {
            bf16x8 bhv = bh[ct * 64];
            bf16x8 blv = bl[ct * 64];
            acc[ct] = __builtin_amdgcn_mfma_f32_16x16x32_bf16(ah, bhv, acc[ct], 0, 0, 0);
            acc[ct] = __builtin_amdgcn_mfma_f32_16x16x32_bf16(ah, blv, acc[ct], 0, 0, 0);
            acc[ct] = __builtin_amdgcn_mfma_f32_16x16x32_bf16(al, bhv, acc[ct], 0, 0, 0);
        }
    }

    int rbase = rowbase + ((lane >> 4) << 2);
    int col = lane & 15;
    #pragma unroll
    for (int ct = 0; ct < 8; ++ct) {
        #pragma unroll
        for (int i = 0; i < 4; ++i) {
            int row = rbase + i;
            if (row < N_NODES) h[(size_t)row * 128 + ct * 16 + col] = f2bf_rn(acc[ct][i]);
        }
    }
}

// ---------------- gather-aggregate (wave per node, bf16 h, u16 CSR, unroll 8) ----------------

__global__ __launch_bounds__(256) void aggregate(const unsigned int* __restrict__ hu,
                                                 const int* __restrict__ row_start,
                                                 const unsigned short* __restrict__ ssrc16,
                                                 const float* __restrict__ dinv,
                                                 const float* __restrict__ bias,
                                                 float* __restrict__ out) {
    int node = blockIdx.x * 4 + (threadIdx.x >> 6);
    int lane = threadIdx.x & 63;
    if (node >= N_NODES) return;
    int s = row_start[node];
    int t = row_start[node + 1];
    float accx = 0.f, accy = 0.f;
    for (int base = s; base < t; base += 64) {
        int c = t - base;
        if (c > 64) c = 64;
        int li = base + (lane < c ? lane : c - 1);
        int idx = (int)ssrc16[li];
        float dv = dinv[idx];
        int j = 0;
        for (; j + 8 <= c; j += 8) {
            int ss[8]; float dd[8]; unsigned uu[8];
            #pragma unroll
            for (int k = 0; k < 8; ++k) {
                ss[k] = __shfl(idx, j + k);
                dd[k] = __shfl(dv, j + k);
            }
            #pragma unroll
            for (int k = 0; k < 8; ++k) uu[k] = hu[(size_t)ss[k] * 64 + lane];
            #pragma unroll
            for (int k = 0; k < 8; ++k) {
                accx += dd[k] * __uint_as_float(uu[k] << 16);
                accy += dd[k] * __uint_as_float(uu[k] & 0xffff0000u);
            }
        }
        for (; j < c; ++j) {
            int sj = __shfl(idx, j);
            float dj = __shfl(dv, j);
            unsigned u = hu[(size_t)sj * 64 + lane];
            accx += dj * __uint_as_float(u << 16);
            accy += dj * __uint_as_float(u & 0xffff0000u);
        }
    }
    float di = dinv[node];
    unsigned us = hu[(size_t)node * 64 + lane];
    float2 bv = *(const float2*)&bias[2 * lane];
    float2 o;
    o.x = di * accx + di * di * __uint_as_float(us << 16) + bv.x;
    o.y = di * accy + di * di * __uint_as_float(us & 0xffff0000u) + bv.y;
    *(float2*)&out[(size_t)node * 128 + 2 * lane] = o;
}

// ---------------- launch ----------------

extern "C" void kernel_launch(void* const* d_in, const int* in_sizes, int n_in,
                              void* d_out, int out_size, void* d_ws, size_t ws_size,
                              hipStream_t stream) {
    const float* x  = (const float*)d_in[0];
    const int*   ei = (const int*)d_in[1];
    const float* W  = (const float*)d_in[2];
    const float* b  = (const float*)d_in[3];
    float* out = (float*)d_out;

    char* ws = (char*)d_ws;
    // part aliases h's prefix: part is dead after csr_build, h written after by gemm.
    unsigned short* h      = (unsigned short*)(ws + 0);        // 12,800,000
    unsigned int*   part   = (unsigned int*)  (ws + 0);        //  6,422,528 (alias)
    int*   row_start       = (int*)  (ws + 12800000);          //    200,004
    float* dinv            = (float*)(ws + 13000016);          //    200,000
    unsigned short* ssrc16 = (unsigned short*)(ws + 13200016); //  1,600,000
    int*   gcur            = (int*)  (ws + 14800016);          //      1,568
    unsigned short* wH     = (unsigned short*)(ws + 14801600); //     32,768
    unsigned short* wL     = (unsigned short*)(ws + 14834368); //     32,768

    hipLaunchKernelGGL(setup,        dim3(9),      dim3(256), 0, stream, W, wH, wL, gcur, row_start);
    hipLaunchKernelGGL(partition,    dim3(NCHUNK), dim3(256), 0, stream, ei, gcur, part);
    hipLaunchKernelGGL(csr_build,    dim3(NBKT),   dim3(256), 0, stream, part, gcur, row_start, dinv, ssrc16);
    hipLaunchKernelGGL(gemm_xw_mfma, dim3((N_NODES + 63) / 64), dim3(256), 0, stream, x, wH, wL, h);
    hipLaunchKernelGGL(aggregate,    dim3((N_NODES + 3) / 4), dim3(256), 0, stream,
                       (const unsigned int*)h, row_start, ssrc16, dinv, b, out);
}

// Round 10
// 139.008 us; speedup vs baseline: 3.8054x; 1.0756x over previous
//
#include <hip/hip_runtime.h>
#include <math.h>

#define N_NODES 50000
#define N_EDGES 800000
#define D 128
#define NBKT 392            // buckets of 128 dst nodes: 392*128 = 50176 >= 50000
#define CHUNK 4096          // edges per partition block
#define NCHUNK ((N_EDGES + CHUNK - 1) / CHUNK)   // 196
#define CAPB 4096           // partition slot capacity per bucket
#define GEMM_BLOCKS ((N_NODES + 63) / 64)        // 782

typedef short bf16x8 __attribute__((ext_vector_type(8)));
typedef float f32x4 __attribute__((ext_vector_type(4)));

static __device__ __forceinline__ unsigned short f2bf_rn(float f) {
    unsigned u = __float_as_uint(f);
    unsigned r = (u + 0x7FFF + ((u >> 16) & 1)) >> 16;
    return (unsigned short)r;
}
static __device__ __forceinline__ float bf2f(unsigned short h) {
    return __uint_as_float(((unsigned)h) << 16);
}

// ---------------- setup: W fragments (blocks 0-7) + gcur init (block 8) ----------------

__global__ __launch_bounds__(256) void setup(const float* __restrict__ W,
                                             unsigned short* __restrict__ wH,
                                             unsigned short* __restrict__ wL,
                                             int* __restrict__ gcur,
                                             int* __restrict__ row_start) {
    if (blockIdx.x < 8) {
        int tid = blockIdx.x * 256 + threadIdx.x;   // 0..2047
        int kstep = tid >> 9;
        int ct = (tid >> 6) & 7;
        int lane = tid & 63;
        int kbase = kstep * 32 + ((lane >> 4) << 3);
        int c = ct * 16 + (lane & 15);
        #pragma unroll
        for (int e = 0; e < 8; ++e) {
            float v = W[(kbase + e) * 128 + c];
            unsigned short hb = f2bf_rn(v);
            float res = v - bf2f(hb);
            wH[tid * 8 + e] = hb;
            wL[tid * 8 + e] = f2bf_rn(res);
        }
    } else {
        for (int j = threadIdx.x; j < NBKT; j += 256) gcur[j] = j * CAPB;
        if (threadIdx.x == 0) row_start[N_NODES] = N_EDGES;
    }
}

// ---------------- fat kernel: partition (blocks 0..195) || gemm (blocks 196..977) ----------------
// partition: chunk of 4096 edges -> LDS hist/scan/placement -> one atomic per bucket ->
//            coalesced flush into fixed bucket regions of part[] (NOT aliasing h).
// gemm: h = x @ W via bf16x3 split MFMA, bf16 output. Independent of partition.

__global__ __launch_bounds__(256) void part_gemm(const int* __restrict__ ei,
                                                 int* __restrict__ gcur,
                                                 unsigned int* __restrict__ part,
                                                 const float* __restrict__ x,
                                                 const unsigned short* __restrict__ wH,
                                                 const unsigned short* __restrict__ wL,
                                                 unsigned short* __restrict__ h) {
    __shared__ unsigned int ebuf[CHUNK];   // 16 KB
    __shared__ unsigned int obuf[CHUNK];   // 16 KB
    __shared__ int hist[NBKT];
    __shared__ int spos[NBKT];
    __shared__ int goff[NBKT];
    __shared__ int sm[256];
    int t = threadIdx.x;

    if (blockIdx.x < NCHUNK) {
        // ---------------- partition body ----------------
        int base = blockIdx.x * CHUNK;
        int n = N_EDGES - base; if (n > CHUNK) n = CHUNK;

        for (int j = t; j < NBKT; j += 256) hist[j] = 0;
        __syncthreads();
        for (int i = t; i < n; i += 256) {
            unsigned s = (unsigned)ei[base + i];
            unsigned d = (unsigned)ei[N_EDGES + base + i];
            ebuf[i] = s | (d << 16);
            atomicAdd(&hist[d >> 7], 1);
        }
        __syncthreads();
        int i0 = 2 * t, i1 = i0 + 1;
        int a = (i0 < NBKT) ? hist[i0] : 0;
        int b = (i1 < NBKT) ? hist[i1] : 0;
        int ps = a + b;
        sm[t] = ps; __syncthreads();
        for (int o = 1; o < 256; o <<= 1) {
            int ad = (t >= o) ? sm[t - o] : 0;
            __syncthreads();
            sm[t] += ad;
            __syncthreads();
        }
        int ex = sm[t] - ps;
        if (i0 < NBKT) spos[i0] = ex;
        if (i1 < NBKT) spos[i1] = ex + a;
        __syncthreads();
        for (int j = t; j < NBKT; j += 256) {
            int gp = atomicAdd(&gcur[j], hist[j]);
            goff[j] = gp - spos[j];
        }
        __syncthreads();
        for (int j = t; j < NBKT; j += 256) hist[j] = 0;
        __syncthreads();
        for (int i = t; i < n; i += 256) {
            unsigned e = ebuf[i];
            int bk = e >> 23;
            int p = spos[bk] + atomicAdd(&hist[bk], 1);
            obuf[p] = e;
        }
        __syncthreads();
        for (int i = t; i < n; i += 256) {
            unsigned e = obuf[i];
            int bk = e >> 23;
            part[goff[bk] + i] = e;
        }
    } else {
        // ---------------- gemm body ----------------
        int gb = blockIdx.x - NCHUNK;
        int wave = t >> 6;
        int lane = t & 63;
        int rowbase = gb * 64 + wave * 16;

        f32x4 acc[8];
        #pragma unroll
        for (int ct = 0; ct < 8; ++ct) acc[ct] = (f32x4)(0.f);

        int arow = rowbase + (lane & 15);
        if (arow >= N_NODES) arow = N_NODES - 1;
        const float* xrow = x + (size_t)arow * 128 + ((lane >> 4) << 3);

        #pragma unroll
        for (int kstep = 0; kstep < 4; ++kstep) {
            float4 a0 = *(const float4*)(xrow + kstep * 32);
            float4 a1 = *(const float4*)(xrow + kstep * 32 + 4);
            float av[8] = {a0.x, a0.y, a0.z, a0.w, a1.x, a1.y, a1.z, a1.w};
            bf16x8 ah, al;
            #pragma unroll
            for (int e = 0; e < 8; ++e) {
                unsigned short hb = f2bf_rn(av[e]);
                float res = av[e] - bf2f(hb);
                ah[e] = (short)hb;
                al[e] = (short)f2bf_rn(res);
            }
            const bf16x8* bh = (const bf16x8*)(wH + (size_t)(kstep * 8) * 64 * 8 + lane * 8);
            const bf16x8* bl = (const bf16x8*)(wL + (size_t)(kstep * 8) * 64 * 8 + lane * 8);
            #pragma unroll
            for (int ct = 0; ct < 8; ++ct) {
                bf16x8 bhv = bh[ct * 64];
                bf16x8 blv = bl[ct * 64];
                acc[ct] = __builtin_amdgcn_mfma_f32_16x16x32_bf16(ah, bhv, acc[ct], 0, 0, 0);
                acc[ct] = __builtin_amdgcn_mfma_f32_16x16x32_bf16(ah, blv, acc[ct], 0, 0, 0);
                acc[ct] = __builtin_amdgcn_mfma_f32_16x16x32_bf16(al, bhv, acc[ct], 0, 0, 0);
            }
        }

        int rbase = rowbase + ((lane >> 4) << 2);
        int col = lane & 15;
        #pragma unroll
        for (int ct = 0; ct < 8; ++ct) {
            #pragma unroll
            for (int i = 0; i < 4; ++i) {
                int row = rbase + i;
                if (row < N_NODES) h[(size_t)row * 128 + ct * 16 + col] = f2bf_rn(acc[ct][i]);
            }
        }
    }
}

// ---------------- per-bucket CSR build (self-computed prefix, LDS image) ----------------

__global__ __launch_bounds__(256) void csr_build(const unsigned int* __restrict__ part,
                                                 const int* __restrict__ gcur,
                                                 int* __restrict__ row_start,
                                                 float* __restrict__ dinv,
                                                 unsigned short* __restrict__ ssrc16) {
    __shared__ unsigned int ebuf[CAPB];        // 16 KB
    __shared__ unsigned short img[CAPB];       // 8 KB
    __shared__ int exf[NBKT];
    __shared__ int sm2[256];
    __shared__ int h128[128];
    __shared__ int loff[128];
    __shared__ int sm[128];
    int t = threadIdx.x;
    int b = blockIdx.x;

    int i0 = 2 * t, i1 = i0 + 1;
    int a = (i0 < NBKT) ? (gcur[i0] - i0 * CAPB) : 0;
    int b2 = (i1 < NBKT) ? (gcur[i1] - i1 * CAPB) : 0;
    int ps = a + b2;
    sm2[t] = ps; __syncthreads();
    for (int o = 1; o < 256; o <<= 1) {
        int ad = (t >= o) ? sm2[t - o] : 0;
        __syncthreads();
        sm2[t] += ad;
        __syncthreads();
    }
    int ex = sm2[t] - ps;
    if (i0 < NBKT) exf[i0] = ex;
    if (i1 < NBKT) exf[i1] = ex + a;
    for (int j = t; j < 128; j += 256) h128[j] = 0;
    __syncthreads();

    int cnt = gcur[b] - b * CAPB;
    int cb = exf[b];
    int gb = b * CAPB;
    int nbase = b * 128;

    for (int i = t; i < cnt; i += 256) {
        unsigned e = part[gb + i];
        ebuf[i] = e;
        atomicAdd(&h128[(e >> 16) & 127], 1);
    }
    __syncthreads();
    if (t < 128) sm[t] = h128[t];
    __syncthreads();
    for (int o = 1; o < 128; o <<= 1) {
        int ad = 0;
        if (t < 128 && t >= o) ad = sm[t - o];
        __syncthreads();
        if (t < 128) sm[t] += ad;
        __syncthreads();
    }
    if (t < 128) {
        int exl = sm[t] - h128[t];
        loff[t] = exl;
        int node = nbase + t;
        if (node < N_NODES) {
            row_start[node] = cb + exl;
            dinv[node] = rsqrtf((float)(h128[t] + 1));
        }
        h128[t] = 0;   // reuse as placement cursor
    }
    __syncthreads();
    for (int i = t; i < cnt; i += 256) {
        unsigned e = ebuf[i];
        int j = (e >> 16) & 127;
        int p = loff[j] + atomicAdd(&h128[j], 1);
        img[p] = (unsigned short)(e & 0xffffu);
    }
    __syncthreads();
    for (int i = t; i < cnt; i += 256) ssrc16[cb + i] = img[i];
}

// ---------------- gather-aggregate (wave per node, bf16 h, u16 CSR, unroll 8) ----------------

__global__ __launch_bounds__(256) void aggregate(const unsigned int* __restrict__ hu,
                                                 const int* __restrict__ row_start,
                                                 const unsigned short* __restrict__ ssrc16,
                                                 const float* __restrict__ dinv,
                                                 const float* __restrict__ bias,
                                                 float* __restrict__ out) {
    int node = blockIdx.x * 4 + (threadIdx.x >> 6);
    int lane = threadIdx.x & 63;
    if (node >= N_NODES) return;
    int s = row_start[node];
    int t = row_start[node + 1];
    float accx = 0.f, accy = 0.f;
    for (int base = s; base < t; base += 64) {
        int c = t - base;
        if (c > 64) c = 64;
        int li = base + (lane < c ? lane : c - 1);
        int idx = (int)ssrc16[li];
        float dv = dinv[idx];
        int j = 0;
        for (; j + 8 <= c; j += 8) {
            int ss[8]; float dd[8]; unsigned uu[8];
            #pragma unroll
            for (int k = 0; k < 8; ++k) {
                ss[k] = __shfl(idx, j + k);
                dd[k] = __shfl(dv, j + k);
            }
            #pragma unroll
            for (int k = 0; k < 8; ++k) uu[k] = hu[(size_t)ss[k] * 64 + lane];
            #pragma unroll
            for (int k = 0; k < 8; ++k) {
                accx += dd[k] * __uint_as_float(uu[k] << 16);
                accy += dd[k] * __uint_as_float(uu[k] & 0xffff0000u);
            }
        }
        for (; j < c; ++j) {
            int sj = __shfl(idx, j);
            float dj = __shfl(dv, j);
            unsigned u = hu[(size_t)sj * 64 + lane];
            accx += dj * __uint_as_float(u << 16);
            accy += dj * __uint_as_float(u & 0xffff0000u);
        }
    }
    float di = dinv[node];
    unsigned us = hu[(size_t)node * 64 + lane];
    float2 bv = *(const float2*)&bias[2 * lane];
    float2 o;
    o.x = di * accx + di * di * __uint_as_float(us << 16) + bv.x;
    o.y = di * accy + di * di * __uint_as_float(us & 0xffff0000u) + bv.y;
    *(float2*)&out[(size_t)node * 128 + 2 * lane] = o;
}

// ---------------- launch ----------------

extern "C" void kernel_launch(void* const* d_in, const int* in_sizes, int n_in,
                              void* d_out, int out_size, void* d_ws, size_t ws_size,
                              hipStream_t stream) {
    const float* x  = (const float*)d_in[0];
    const int*   ei = (const int*)d_in[1];
    const float* W  = (const float*)d_in[2];
    const float* b  = (const float*)d_in[3];
    float* out = (float*)d_out;

    char* ws = (char*)d_ws;
    // NOTE: part must NOT alias h — partition and gemm run concurrently in part_gemm.
    unsigned short* h      = (unsigned short*)(ws + 0);        // 12,800,000
    int*   row_start       = (int*)  (ws + 12800000);          //    200,004
    float* dinv            = (float*)(ws + 13000016);          //    200,000
    unsigned short* ssrc16 = (unsigned short*)(ws + 13200016); //  1,600,000
    int*   gcur            = (int*)  (ws + 14800016);          //      1,568
    unsigned short* wH     = (unsigned short*)(ws + 14801600); //     32,768
    unsigned short* wL     = (unsigned short*)(ws + 14834368); //     32,768
    unsigned int*   part   = (unsigned int*)  (ws + 14867200); //  6,422,528 (disjoint)

    hipLaunchKernelGGL(setup,     dim3(9),                  dim3(256), 0, stream, W, wH, wL, gcur, row_start);
    hipLaunchKernelGGL(part_gemm, dim3(NCHUNK + GEMM_BLOCKS), dim3(256), 0, stream,
                       ei, gcur, part, x, wH, wL, h);
    hipLaunchKernelGGL(csr_build, dim3(NBKT),               dim3(256), 0, stream, part, gcur, row_start, dinv, ssrc16);
    hipLaunchKernelGGL(aggregate, dim3((N_NODES + 3) / 4),  dim3(256), 0, stream,
                       (const unsigned int*)h, row_start, ssrc16, dinv, b, out);
}

// Round 11
// 137.782 us; speedup vs baseline: 3.8393x; 1.0089x over previous
//
#include <hip/hip_runtime.h>
#include <math.h>

#define N_NODES 50000
#define N_EDGES 800000
#define D 128
#define NBKT 392            // buckets of 128 dst nodes: 392*128 = 50176 >= 50000
#define CHUNK 4096          // edges per partition block
#define NCHUNK ((N_EDGES + CHUNK - 1) / CHUNK)   // 196
#define CAPB 4096           // partition slot capacity per bucket
#define GEMM_BLOCKS ((N_NODES + 63) / 64)        // 782

typedef short bf16x8 __attribute__((ext_vector_type(8)));
typedef float f32x4 __attribute__((ext_vector_type(4)));

static __device__ __forceinline__ unsigned short f2bf_rn(float f) {
    unsigned u = __float_as_uint(f);
    unsigned r = (u + 0x7FFF + ((u >> 16) & 1)) >> 16;
    return (unsigned short)r;
}
static __device__ __forceinline__ float bf2f(unsigned short h) {
    return __uint_as_float(((unsigned)h) << 16);
}

// ---------------- setup: W hi-fragments (blocks 0-7) + gcur/row_start init (block 8) ----
// W fragment for mfma_f32_16x16x32_bf16 B operand: lane l of frag (kstep, ctile) holds
// B[k = kstep*32 + (l>>4)*8 + e][c = ctile*16 + (l&15)], e = 0..7.
// bf16x2 scheme: h = (xh + xl) * wh  (W residual dropped; x residual kept).

__global__ __launch_bounds__(256) void setup(const float* __restrict__ W,
                                             unsigned short* __restrict__ wH,
                                             int* __restrict__ gcur,
                                             int* __restrict__ row_start) {
    if (blockIdx.x < 8) {
        int tid = blockIdx.x * 256 + threadIdx.x;   // 0..2047
        int kstep = tid >> 9;
        int ct = (tid >> 6) & 7;
        int lane = tid & 63;
        int kbase = kstep * 32 + ((lane >> 4) << 3);
        int c = ct * 16 + (lane & 15);
        #pragma unroll
        for (int e = 0; e < 8; ++e) {
            wH[tid * 8 + e] = f2bf_rn(W[(kbase + e) * 128 + c]);
        }
    } else {
        for (int j = threadIdx.x; j < NBKT; j += 256) gcur[j] = j * CAPB;
        if (threadIdx.x == 0) row_start[N_NODES] = N_EDGES;
    }
}

// ---------------- fat kernel: partition (blocks 0..195) || gemm (blocks 196..977) --------

__global__ __launch_bounds__(256) void part_gemm(const int* __restrict__ ei,
                                                 int* __restrict__ gcur,
                                                 unsigned int* __restrict__ part,
                                                 const float* __restrict__ x,
                                                 const unsigned short* __restrict__ wH,
                                                 unsigned short* __restrict__ h) {
    __shared__ unsigned int ebuf[CHUNK];   // 16 KB
    __shared__ unsigned int obuf[CHUNK];   // 16 KB
    __shared__ int hist[NBKT];
    __shared__ int spos[NBKT];
    __shared__ int goff[NBKT];
    __shared__ int sm[256];
    int t = threadIdx.x;

    if (blockIdx.x < NCHUNK) {
        // ---------------- partition body ----------------
        int base = blockIdx.x * CHUNK;
        int n = N_EDGES - base; if (n > CHUNK) n = CHUNK;

        for (int j = t; j < NBKT; j += 256) hist[j] = 0;
        __syncthreads();
        for (int i = t; i < n; i += 256) {
            unsigned s = (unsigned)ei[base + i];
            unsigned d = (unsigned)ei[N_EDGES + base + i];
            ebuf[i] = s | (d << 16);
            atomicAdd(&hist[d >> 7], 1);
        }
        __syncthreads();
        int i0 = 2 * t, i1 = i0 + 1;
        int a = (i0 < NBKT) ? hist[i0] : 0;
        int b = (i1 < NBKT) ? hist[i1] : 0;
        int ps = a + b;
        sm[t] = ps; __syncthreads();
        for (int o = 1; o < 256; o <<= 1) {
            int ad = (t >= o) ? sm[t - o] : 0;
            __syncthreads();
            sm[t] += ad;
            __syncthreads();
        }
        int ex = sm[t] - ps;
        if (i0 < NBKT) spos[i0] = ex;
        if (i1 < NBKT) spos[i1] = ex + a;
        __syncthreads();
        for (int j = t; j < NBKT; j += 256) {
            int gp = atomicAdd(&gcur[j], hist[j]);
            goff[j] = gp - spos[j];
        }
        __syncthreads();
        for (int j = t; j < NBKT; j += 256) hist[j] = 0;
        __syncthreads();
        for (int i = t; i < n; i += 256) {
            unsigned e = ebuf[i];
            int bk = e >> 23;
            int p = spos[bk] + atomicAdd(&hist[bk], 1);
            obuf[p] = e;
        }
        __syncthreads();
        for (int i = t; i < n; i += 256) {
            unsigned e = obuf[i];
            int bk = e >> 23;
            part[goff[bk] + i] = e;
        }
    } else {
        // ---------------- gemm body: h = (xh + xl) * wh ----------------
        int gb = blockIdx.x - NCHUNK;
        int wave = t >> 6;
        int lane = t & 63;
        int rowbase = gb * 64 + wave * 16;

        f32x4 acc[8];
        #pragma unroll
        for (int ct = 0; ct < 8; ++ct) acc[ct] = (f32x4)(0.f);

        int arow = rowbase + (lane & 15);
        if (arow >= N_NODES) arow = N_NODES - 1;
        const float* xrow = x + (size_t)arow * 128 + ((lane >> 4) << 3);

        #pragma unroll
        for (int kstep = 0; kstep < 4; ++kstep) {
            float4 a0 = *(const float4*)(xrow + kstep * 32);
            float4 a1 = *(const float4*)(xrow + kstep * 32 + 4);
            float av[8] = {a0.x, a0.y, a0.z, a0.w, a1.x, a1.y, a1.z, a1.w};
            bf16x8 ah, al;
            #pragma unroll
            for (int e = 0; e < 8; ++e) {
                unsigned short hb = f2bf_rn(av[e]);
                float res = av[e] - bf2f(hb);
                ah[e] = (short)hb;
                al[e] = (short)f2bf_rn(res);
            }
            const bf16x8* bh = (const bf16x8*)(wH + (size_t)(kstep * 8) * 64 * 8 + lane * 8);
            #pragma unroll
            for (int ct = 0; ct < 8; ++ct) {
                bf16x8 bhv = bh[ct * 64];
                acc[ct] = __builtin_amdgcn_mfma_f32_16x16x32_bf16(ah, bhv, acc[ct], 0, 0, 0);
                acc[ct] = __builtin_amdgcn_mfma_f32_16x16x32_bf16(al, bhv, acc[ct], 0, 0, 0);
            }
        }

        int rbase = rowbase + ((lane >> 4) << 2);
        int col = lane & 15;
        #pragma unroll
        for (int ct = 0; ct < 8; ++ct) {
            #pragma unroll
            for (int i = 0; i < 4; ++i) {
                int row = rbase + i;
                if (row < N_NODES) h[(size_t)row * 128 + ct * 16 + col] = f2bf_rn(acc[ct][i]);
            }
        }
    }
}

// ---------------- per-bucket CSR build (self-computed prefix, LDS image) ----------------

__global__ __launch_bounds__(256) void csr_build(const unsigned int* __restrict__ part,
                                                 const int* __restrict__ gcur,
                                                 int* __restrict__ row_start,
                                                 float* __restrict__ dinv,
                                                 unsigned short* __restrict__ ssrc16) {
    __shared__ unsigned int ebuf[CAPB];        // 16 KB
    __shared__ unsigned short img[CAPB];       // 8 KB
    __shared__ int exf[NBKT];
    __shared__ int sm2[256];
    __shared__ int h128[128];
    __shared__ int loff[128];
    __shared__ int sm[128];
    int t = threadIdx.x;
    int b = blockIdx.x;

    int i0 = 2 * t, i1 = i0 + 1;
    int a = (i0 < NBKT) ? (gcur[i0] - i0 * CAPB) : 0;
    int b2 = (i1 < NBKT) ? (gcur[i1] - i1 * CAPB) : 0;
    int ps = a + b2;
    sm2[t] = ps; __syncthreads();
    for (int o = 1; o < 256; o <<= 1) {
        int ad = (t >= o) ? sm2[t - o] : 0;
        __syncthreads();
        sm2[t] += ad;
        __syncthreads();
    }
    int ex = sm2[t] - ps;
    if (i0 < NBKT) exf[i0] = ex;
    if (i1 < NBKT) exf[i1] = ex + a;
    for (int j = t; j < 128; j += 256) h128[j] = 0;
    __syncthreads();

    int cnt = gcur[b] - b * CAPB;
    int cb = exf[b];
    int gb = b * CAPB;
    int nbase = b * 128;

    for (int i = t; i < cnt; i += 256) {
        unsigned e = part[gb + i];
        ebuf[i] = e;
        atomicAdd(&h128[(e >> 16) & 127], 1);
    }
    __syncthreads();
    if (t < 128) sm[t] = h128[t];
    __syncthreads();
    for (int o = 1; o < 128; o <<= 1) {
        int ad = 0;
        if (t < 128 && t >= o) ad = sm[t - o];
        __syncthreads();
        if (t < 128) sm[t] += ad;
        __syncthreads();
    }
    if (t < 128) {
        int exl = sm[t] - h128[t];
        loff[t] = exl;
        int node = nbase + t;
        if (node < N_NODES) {
            row_start[node] = cb + exl;
            dinv[node] = rsqrtf((float)(h128[t] + 1));
        }
        h128[t] = 0;   // reuse as placement cursor
    }
    __syncthreads();
    for (int i = t; i < cnt; i += 256) {
        unsigned e = ebuf[i];
        int j = (e >> 16) & 127;
        int p = loff[j] + atomicAdd(&h128[j], 1);
        img[p] = (unsigned short)(e & 0xffffu);
    }
    __syncthreads();
    for (int i = t; i < cnt; i += 256) ssrc16[cb + i] = img[i];
}

// ---------------- gather-aggregate (wave per node, bf16 h, u16 CSR, unroll 8) ----------------

__global__ __launch_bounds__(256) void aggregate(const unsigned int* __restrict__ hu,
                                                 const int* __restrict__ row_start,
                                                 const unsigned short* __restrict__ ssrc16,
                                                 const float* __restrict__ dinv,
                                                 const float* __restrict__ bias,
                                                 float* __restrict__ out) {
    int node = blockIdx.x * 4 + (threadIdx.x >> 6);
    int lane = threadIdx.x & 63;
    if (node >= N_NODES) return;
    int s = row_start[node];
    int t = row_start[node + 1];
    float accx = 0.f, accy = 0.f;
    for (int base = s; base < t; base += 64) {
        int c = t - base;
        if (c > 64) c = 64;
        int li = base + (lane < c ? lane : c - 1);
        int idx = (int)ssrc16[li];
        float dv = dinv[idx];
        int j = 0;
        for (; j + 8 <= c; j += 8) {
            int ss[8]; float dd[8]; unsigned uu[8];
            #pragma unroll
            for (int k = 0; k < 8; ++k) {
                ss[k] = __shfl(idx, j + k);
                dd[k] = __shfl(dv, j + k);
            }
            #pragma unroll
            for (int k = 0; k < 8; ++k) uu[k] = hu[(size_t)ss[k] * 64 + lane];
            #pragma unroll
            for (int k = 0; k < 8; ++k) {
                accx += dd[k] * __uint_as_float(uu[k] << 16);
                accy += dd[k] * __uint_as_float(uu[k] & 0xffff0000u);
            }
        }
        for (; j < c; ++j) {
            int sj = __shfl(idx, j);
            float dj = __shfl(dv, j);
            unsigned u = hu[(size_t)sj * 64 + lane];
            accx += dj * __uint_as_float(u << 16);
            accy += dj * __uint_as_float(u & 0xffff0000u);
        }
    }
    float di = dinv[node];
    unsigned us = hu[(size_t)node * 64 + lane];
    float2 bv = *(const float2*)&bias[2 * lane];
    float2 o;
    o.x = di * accx + di * di * __uint_as_float(us << 16) + bv.x;
    o.y = di * accy + di * di * __uint_as_float(us & 0xffff0000u) + bv.y;
    *(float2*)&out[(size_t)node * 128 + 2 * lane] = o;
}

// ---------------- launch ----------------

extern "C" void kernel_launch(void* const* d_in, const int* in_sizes, int n_in,
                              void* d_out, int out_size, void* d_ws, size_t ws_size,
                              hipStream_t stream) {
    const float* x  = (const float*)d_in[0];
    const int*   ei = (const int*)d_in[1];
    const float* W  = (const float*)d_in[2];
    const float* b  = (const float*)d_in[3];
    float* out = (float*)d_out;

    char* ws = (char*)d_ws;
    // NOTE: part must NOT alias h — partition and gemm run concurrently in part_gemm.
    unsigned short* h      = (unsigned short*)(ws + 0);        // 12,800,000
    int*   row_start       = (int*)  (ws + 12800000);          //    200,004
    float* dinv            = (float*)(ws + 13000016);          //    200,000
    unsigned short* ssrc16 = (unsigned short*)(ws + 13200016); //  1,600,000
    int*   gcur            = (int*)  (ws + 14800016);          //      1,568
    unsigned short* wH     = (unsigned short*)(ws + 14801600); //     32,768
    unsigned int*   part   = (unsigned int*)  (ws + 14834368); //  6,422,528 (disjoint)

    hipLaunchKernelGGL(setup,     dim3(9),                    dim3(256), 0, stream, W, wH, gcur, row_start);
    hipLaunchKernelGGL(part_gemm, dim3(NCHUNK + GEMM_BLOCKS), dim3(256), 0, stream,
                       ei, gcur, part, x, wH, h);
    hipLaunchKernelGGL(csr_build, dim3(NBKT),                 dim3(256), 0, stream, part, gcur, row_start, dinv, ssrc16);
    hipLaunchKernelGGL(aggregate, dim3((N_NODES + 3) / 4),    dim3(256), 0, stream,
                       (const unsigned int*)h, row_start, ssrc16, dinv, b, out);
}